// Round 8
// baseline (125.564 us; speedup 1.0000x reference)
//
#include <hip/hip_runtime.h>
#include <math.h>

#define B_    2
#define T_    2048
#define EMB_  128
#define NH_   8
#define M_    9
#define P_    36
#define GADD_ 2

typedef __attribute__((ext_vector_type(8))) short bf16x8;
typedef __attribute__((ext_vector_type(4))) float f32x4;

// ---------------- Threefry-2x32 (jax PRNG) ----------------
__device__ __forceinline__ unsigned rotl32(unsigned x, int r){ return (x<<r)|(x>>(32-r)); }

struct U2 { unsigned x, y; };

__device__ __forceinline__ U2 tf2x32(U2 key, U2 ctr){
  unsigned ks[3] = { key.x, key.y, key.x ^ key.y ^ 0x1BD11BDAu };
  unsigned x0 = ctr.x + ks[0], x1 = ctr.y + ks[1];
  const int rotA[4] = {13,15,26,6}, rotB[4] = {17,29,16,24};
  #pragma unroll
  for (int r = 0; r < 5; ++r){
    const int* rr = (r & 1) ? rotB : rotA;
    #pragma unroll
    for (int i = 0; i < 4; ++i){ x0 += x1; x1 = rotl32(x1, rr[i]); x1 ^= x0; }
    x0 += ks[(r+1)%3];
    x1 += ks[(r+2)%3] + (unsigned)(r+1);
  }
  return { x0, x1 };
}

// randint(key(42),(B,T,M,GADD),0,T), partitionable threefry path.
__device__ unsigned glob_rand(unsigned f){
  U2 k2 = tf2x32({0u, 42u}, {0u, 1u});
  U2 o  = tf2x32(k2, {0u, f});
  return (o.x ^ o.y) & (unsigned)(T_-1);
}

__device__ __forceinline__ unsigned pack_bf16x2(float a, float b){
  unsigned ua = __float_as_uint(a), ub = __float_as_uint(b);
  ua = ua + 0x7fffu + ((ua >> 16) & 1u);
  ub = ub + 0x7fffu + ((ub >> 16) & 1u);
  return (ua >> 16) | (ub & 0xffff0000u);
}
__device__ __forceinline__ unsigned short bf16r(float f){
  unsigned u = __float_as_uint(f);
  u = u + 0x7fffu + ((u >> 16) & 1u);
  return (unsigned short)(u >> 16);
}
__device__ __forceinline__ float dot2bf(unsigned a, unsigned b, float c){
  float d;
  asm("v_dot2_f32_bf16 %0, %1, %2, %3" : "=v"(d) : "v"(a), "v"(b), "v"(c));
  return d;
}

// ---------------- kernel 0: fused prep (xconv | tconvQKV | tconvWu | idx+weights) ----------------
__device__ __forceinline__ void tconv_body(const float* __restrict__ A,
    unsigned short* __restrict__ o, int R, int C, int r0, int c0, float scale,
    float (*tile)[33]){
  const int tx = threadIdx.x & 31, ty = threadIdx.x >> 5;
  #pragma unroll
  for (int i = 0; i < 32; i += 8)
    tile[ty+i][tx] = A[(size_t)(r0+ty+i)*C + c0+tx];
  __syncthreads();
  #pragma unroll
  for (int i = 0; i < 32; i += 8)
    o[(size_t)(c0+ty+i)*R + (r0+tx)] = bf16r(tile[tx][ty+i] * scale);
}

__global__ __launch_bounds__(256) void prep_kernel(
    const float* __restrict__ x, unsigned short* __restrict__ xh,
    const float* __restrict__ Wq, const float* __restrict__ Wk, const float* __restrict__ Wv,
    unsigned short* __restrict__ WT,
    const float* __restrict__ Wu, unsigned short* __restrict__ WuT,
    const float* __restrict__ sp, const float* __restrict__ mvals,
    int* __restrict__ idx_out, float* __restrict__ w_out){
  __shared__ float tile[32][33];
  __shared__ int   s_idx[P_];
  __shared__ float s_dens[P_][M_];
  __shared__ float s_col[M_];
  const int bid = blockIdx.x;
  const float sc = 0.29730177875068026f; // 128^-0.25

  if (bid < 512){
    const int i = (bid*256 + threadIdx.x)*4;
    float4 v = *(const float4*)(x + i);
    uint2 pck = { pack_bf16x2(v.x, v.y), pack_bf16x2(v.z, v.w) };
    *(uint2*)(xh + i) = pck;
    return;
  }
  if (bid < 896){
    const int zz = bid - 512;
    const int z = zz >> 7, rem = zz & 127;
    const int by = rem >> 5, bx = rem & 31;       // R=128/32=4, C=1024/32=32
    const float* A = (z==0) ? Wq : (z==1) ? Wk : Wv;
    tconv_body(A, WT + (size_t)z*1024*128, 128, 1024, by*32, bx*32, (z<2)?sc:1.0f, tile);
    return;
  }
  if (bid < 1024){
    const int idx2 = bid - 896;
    const int by = idx2 >> 2, bx = idx2 & 3;      // R=1024/32=32, C=128/32=4
    tconv_body(Wu, WuT, 1024, 128, by*32, bx*32, 1.0f, tile);
    return;
  }

  // ---- idx + weights: bt = bid - 1024 ----
  const int bt = bid - 1024;
  const int t  = bt & (T_-1);
  const int p  = threadIdx.x;

  const float dil  = sp[0];
  const float xs   = sp[1] + 2.0f;
  const float sigma = xs + log1pf(expf(-xs)) + 1e-7f;

  if (p < P_){
    const int m = p >> 2, j = p & 3;
    const float mean = fminf(fmaxf((float)t + (float)(m-4)*dil, 0.f), (float)(T_-1));
    int id;
    if      (j == 0) id = (int)floorf(mean);
    else if (j == 1) id = min((int)floorf(mean) + 1, T_-1);
    else {
      const unsigned f = ((unsigned)bt * M_ + (unsigned)m) * GADD_ + (unsigned)(j-2);
      id = (int)glob_rand(f);
    }
    s_idx[p] = id;
  }
  __syncthreads();
  if (p < P_){
    const int myid = s_idx[p];
    bool dup = false;
    for (int q = 0; q < p; ++q) dup |= (s_idx[q] == myid);
    const float pf = (float)myid;
    #pragma unroll
    for (int m = 0; m < M_; ++m){
      const float mean = fminf(fmaxf((float)t + (float)(m-4)*dil, 0.f), (float)(T_-1));
      const float d = (pf - mean) / sigma;
      s_dens[p][m] = dup ? 0.f : expf(-0.5f * d * d);
    }
  }
  __syncthreads();
  if (p < M_){
    float s = 0.f;
    for (int q = 0; q < P_; ++q) s += s_dens[q][p];
    s_col[p] = s;
  }
  __syncthreads();
  if (p < P_){
    float w = 0.f;
    #pragma unroll
    for (int m = 0; m < M_; ++m) w += s_dens[p][m] / s_col[m] * mvals[m];
    idx_out[bt*P_ + p] = s_idx[p];
    w_out[bt*P_ + p]   = w;
  }
}

// ---------------- kernel 2: QKV via MFMA, all outputs bf16 ----------------
// grid (16, 64, 3), 256 thr = 4 waves; wave: 16M x 64N, K=128.
__global__ __launch_bounds__(256) void qkv_mfma_kernel(const unsigned short* __restrict__ xh,
    const unsigned short* __restrict__ WT,
    unsigned short* __restrict__ Qh, unsigned short* __restrict__ Kh,
    unsigned short* __restrict__ Vh){
  const int z  = blockIdx.z;
  const int w  = threadIdx.x >> 6, l = threadIdx.x & 63;
  const int m0 = blockIdx.y*64 + w*16;
  const int n0 = blockIdx.x*64;
  const int lr = l & 15, lk = l >> 4;

  const unsigned short* __restrict__ WTz = WT + (size_t)z * 1024 * 128;
  unsigned short* __restrict__ Outh = (z==0) ? Qh : (z==1) ? Kh : Vh;

  bf16x8 a[4];
  #pragma unroll
  for (int kc = 0; kc < 4; ++kc)
    a[kc] = *(const bf16x8*)(xh + (size_t)(m0+lr)*128 + kc*32 + lk*8);

  f32x4 acc[4] = {};
  #pragma unroll
  for (int nf = 0; nf < 4; ++nf){
    #pragma unroll
    for (int kc = 0; kc < 4; ++kc){
      bf16x8 b = *(const bf16x8*)(WTz + (size_t)(n0+nf*16+lr)*128 + kc*32 + lk*8);
      acc[nf] = __builtin_amdgcn_mfma_f32_16x16x32_bf16(a[kc], b, acc[nf], 0, 0, 0);
    }
  }
  #pragma unroll
  for (int nf = 0; nf < 4; ++nf){
    const int col = n0 + nf*16 + lr;
    #pragma unroll
    for (int r = 0; r < 4; ++r)
      Outh[(size_t)(m0 + lk*4 + r)*1024 + col] = bf16r(acc[nf][r]);
  }
}

// ---------------- kernel 3: gather-attention (dot2 + 16-lane reduce) ----------------
#define RSTR 37
__global__ __launch_bounds__(512) void attn_kernel(const unsigned short* __restrict__ Qh,
    const unsigned short* __restrict__ K, const unsigned short* __restrict__ V,
    const int* __restrict__ idx, const float* __restrict__ wts,
    unsigned short* __restrict__ outh){
  const int bid = blockIdx.x;
  const int bt  = ((bid & 7) << 9) | (bid >> 3);   // XCD swizzle, bijective
  const int b   = bt >> 11;
  const int h   = threadIdx.x >> 6, lane = threadIdx.x & 63;

  __shared__ int   s_koff[P_];
  __shared__ float s_w[P_];
  __shared__ float s_red[NH_ * 16 * RSTR];
  __shared__ float s_a[NH_][40];

  if (threadIdx.x < P_){
    s_koff[threadIdx.x] = idx[bt*P_ + threadIdx.x] << 10;
    s_w[threadIdx.x]    = wts[bt*P_ + threadIdx.x];
  }
  __syncthreads();

  const size_t rowOff = (size_t)bt*1024 + h*EMB_ + lane*2;
  const unsigned qu = *(const unsigned*)(Qh + rowOff);
  const unsigned short* __restrict__ Kb = K + (size_t)b*T_*1024 + h*EMB_ + lane*2;
  const unsigned short* __restrict__ Vb = V + (size_t)b*T_*1024 + h*EMB_ + lane*2;

  // ---- Phase A: per-lane partial dots, v_dot2_f32_bf16 ----
  const float fzero = 0.f;
  float pr[P_];
  #pragma unroll
  for (int c = 0; c < 4; ++c){
    unsigned u[9]; int ko[9];
    #pragma unroll
    for (int j = 0; j < 9; ++j) ko[j] = s_koff[c*9+j];
    #pragma unroll
    for (int j = 0; j < 9; ++j) u[j] = *(const unsigned*)(Kb + ko[j]);
    #pragma unroll
    for (int j = 0; j < 9; ++j) pr[c*9+j] = dot2bf(qu, u[j], fzero);
  }

  // ---- Phase B: fold 64->16 lanes, LDS transpose, column sum ----
  #pragma unroll
  for (int p = 0; p < P_; ++p) pr[p] += __shfl_xor(pr[p], 32);
  #pragma unroll
  for (int p = 0; p < P_; ++p) pr[p] += __shfl_xor(pr[p], 16);

  float* __restrict__ myred = &s_red[h * 16 * RSTR];
  if (lane < 16){
    float* dst = myred + lane * RSTR;
    #pragma unroll
    for (int i = 0; i < 18; ++i){
      float2 v2 = { pr[2*i], pr[2*i+1] };
      *(float2*)(dst + 2*i) = v2;
    }
  }
  const int pcol = (lane < P_) ? lane : 0;
  float s0=0.f, s1=0.f, s2=0.f, s3=0.f;
  #pragma unroll
  for (int r = 0; r < 16; r += 4){
    s0 += myred[(r+0)*RSTR + pcol];
    s1 += myred[(r+1)*RSTR + pcol];
    s2 += myred[(r+2)*RSTR + pcol];
    s3 += myred[(r+3)*RSTR + pcol];
  }
  const float logit = (s0+s1)+(s2+s3);

  // ---- softmax (lane-per-point) ----
  float val = (lane < P_) ? logit * s_w[pcol] : -INFINITY;
  float mx = val;
  #pragma unroll
  for (int off = 32; off; off >>= 1) mx = fmaxf(mx, __shfl_xor(mx, off));
  float e = (lane < P_) ? expf(val - mx) : 0.f;
  float s = e;
  #pragma unroll
  for (int off = 32; off; off >>= 1) s += __shfl_xor(s, off);
  if (lane < P_) s_a[h][lane] = e / s;

  // ---- Phase C: PV gather with broadcast weights ----
  float2 acc = {0.f, 0.f};
  #pragma unroll
  for (int c = 0; c < 9; ++c){
    const float4 av = *(const float4*)(&s_a[h][4*c]);
    unsigned u[4]; int ko[4];
    #pragma unroll
    for (int j = 0; j < 4; ++j) ko[j] = s_koff[c*4+j];
    #pragma unroll
    for (int j = 0; j < 4; ++j) u[j] = *(const unsigned*)(Vb + ko[j]);
    const float a0 = av.x, a1 = av.y, a2 = av.z, a3 = av.w;
    acc.x += a0*__uint_as_float(u[0] << 16); acc.y += a0*__uint_as_float(u[0] & 0xffff0000u);
    acc.x += a1*__uint_as_float(u[1] << 16); acc.y += a1*__uint_as_float(u[1] & 0xffff0000u);
    acc.x += a2*__uint_as_float(u[2] << 16); acc.y += a2*__uint_as_float(u[2] & 0xffff0000u);
    acc.x += a3*__uint_as_float(u[3] << 16); acc.y += a3*__uint_as_float(u[3] & 0xffff0000u);
  }
  *(unsigned*)(outh + rowOff) = pack_bf16x2(acc.x, acc.y);
}

// ---------------- kernel 4: output GEMM via MFMA + bias ----------------
// out(4096x128) = attnh(4096x1024) @ Wu + bu; WuT[128][1024] bf16.
// grid (8, 64), 256 thr = 4 waves; wave: one 16x16 tile, K=1024, 2 acc chains.
__global__ __launch_bounds__(256) void out_mfma_kernel(const unsigned short* __restrict__ Ah,
    const unsigned short* __restrict__ WuT, const float* __restrict__ bu,
    float* __restrict__ out){
  const int w  = threadIdx.x >> 6, l = threadIdx.x & 63;
  const int m0 = blockIdx.y*64 + w*16;
  const int n0 = blockIdx.x*16;
  const int lr = l & 15, lk = l >> 4;

  const unsigned short* __restrict__ arow = Ah  + (size_t)(m0+lr)*1024 + lk*8;
  const unsigned short* __restrict__ brow = WuT + (size_t)(n0+lr)*1024 + lk*8;

  f32x4 accA = {}, accB = {};
  #pragma unroll 8
  for (int kc = 0; kc < 32; kc += 2){
    bf16x8 a0 = *(const bf16x8*)(arow + kc*32);
    bf16x8 b0 = *(const bf16x8*)(brow + kc*32);
    accA = __builtin_amdgcn_mfma_f32_16x16x32_bf16(a0, b0, accA, 0, 0, 0);
    bf16x8 a1 = *(const bf16x8*)(arow + (kc+1)*32);
    bf16x8 b1 = *(const bf16x8*)(brow + (kc+1)*32);
    accB = __builtin_amdgcn_mfma_f32_16x16x32_bf16(a1, b1, accB, 0, 0, 0);
  }
  const int c0 = n0 + lr;
  const float bias = bu[c0];
  #pragma unroll
  for (int r = 0; r < 4; ++r){
    const size_t row = (size_t)(m0 + lk*4 + r);
    out[row*128 + c0] = (accA[r] + accB[r]) + bias;
  }
}

// ---------------- launch ----------------
extern "C" void kernel_launch(void* const* d_in, const int* in_sizes, int n_in,
                              void* d_out, int out_size, void* d_ws, size_t ws_size,
                              hipStream_t stream){
  (void)in_sizes; (void)n_in; (void)out_size; (void)ws_size;
  const float* x    = (const float*)d_in[0];
  const float* sp   = (const float*)d_in[1];
  const float* mvl  = (const float*)d_in[2];
  const float* Wq   = (const float*)d_in[3];
  const float* Wk   = (const float*)d_in[4];
  const float* Wv   = (const float*)d_in[5];
  const float* Wu   = (const float*)d_in[6];
  const float* bu   = (const float*)d_in[7];
  float* out = (float*)d_out;

  const size_t n = (size_t)B_*NH_*T_*EMB_;               // 4,194,304
  unsigned short* Qh    = (unsigned short*)d_ws;         // n bf16
  unsigned short* Kh    = Qh + n;                        // n bf16
  unsigned short* Vh    = Kh + n;                        // n bf16
  unsigned short* attnh = Vh + n;                        // n bf16
  unsigned short* xh    = attnh + n;                     // 524288 bf16
  unsigned short* WT    = xh + (size_t)B_*T_*EMB_;       // 3*131072 bf16
  unsigned short* WuT   = WT + 3*131072;                 // 131072 bf16
  int*            idxb  = (int*)(WuT + 131072);
  float*          wb    = (float*)(idxb + (size_t)B_*T_*P_);

  prep_kernel<<<5120, 256, 0, stream>>>(x, xh, Wq, Wk, Wv, WT, Wu, WuT, sp, mvl, idxb, wb);
  qkv_mfma_kernel<<<dim3(16, 64, 3), 256, 0, stream>>>(xh, WT, Qh, Kh, Vh);
  attn_kernel<<<B_*T_, 512, 0, stream>>>(Qh, Kh, Vh, idxb, wb, attnh);
  out_mfma_kernel<<<dim3(8, 64), 256, 0, stream>>>(attnh, WuT, bu, out);
}

// Round 10
// 106.629 us; speedup vs baseline: 1.1776x; 1.1776x over previous
//
#include <hip/hip_runtime.h>
#include <math.h>

#define B_    2
#define T_    2048
#define EMB_  128
#define NH_   8
#define M_    9
#define P_    36
#define GADD_ 2

typedef __attribute__((ext_vector_type(8))) short bf16x8;
typedef __attribute__((ext_vector_type(4))) float f32x4;

// ---------------- Threefry-2x32 (jax PRNG) ----------------
__device__ __forceinline__ unsigned rotl32(unsigned x, int r){ return (x<<r)|(x>>(32-r)); }

struct U2 { unsigned x, y; };

__device__ __forceinline__ U2 tf2x32(U2 key, U2 ctr){
  unsigned ks[3] = { key.x, key.y, key.x ^ key.y ^ 0x1BD11BDAu };
  unsigned x0 = ctr.x + ks[0], x1 = ctr.y + ks[1];
  const int rotA[4] = {13,15,26,6}, rotB[4] = {17,29,16,24};
  #pragma unroll
  for (int r = 0; r < 5; ++r){
    const int* rr = (r & 1) ? rotB : rotA;
    #pragma unroll
    for (int i = 0; i < 4; ++i){ x0 += x1; x1 = rotl32(x1, rr[i]); x1 ^= x0; }
    x0 += ks[(r+1)%3];
    x1 += ks[(r+2)%3] + (unsigned)(r+1);
  }
  return { x0, x1 };
}

// randint(key(42),(B,T,M,GADD),0,T), partitionable threefry path.
__device__ unsigned glob_rand(unsigned f){
  U2 k2 = tf2x32({0u, 42u}, {0u, 1u});
  U2 o  = tf2x32(k2, {0u, f});
  return (o.x ^ o.y) & (unsigned)(T_-1);
}

__device__ __forceinline__ unsigned pack_bf16x2(float a, float b){
  unsigned ua = __float_as_uint(a), ub = __float_as_uint(b);
  ua = ua + 0x7fffu + ((ua >> 16) & 1u);
  ub = ub + 0x7fffu + ((ub >> 16) & 1u);
  return (ua >> 16) | (ub & 0xffff0000u);
}
__device__ __forceinline__ unsigned short bf16r(float f){
  unsigned u = __float_as_uint(f);
  u = u + 0x7fffu + ((u >> 16) & 1u);
  return (unsigned short)(u >> 16);
}
__device__ __forceinline__ float bflo(unsigned u){ return __uint_as_float(u << 16); }
__device__ __forceinline__ float bfhi(unsigned u){ return __uint_as_float(u & 0xffff0000u); }

// ---------------- kernel 0: fused prep (xconv | tconvQKV | tconvWu | idx+weights) ----------------
__device__ __forceinline__ void tconv_body(const float* __restrict__ A,
    unsigned short* __restrict__ o, int R, int C, int r0, int c0, float scale,
    float (*tile)[33]){
  const int tx = threadIdx.x & 31, ty = threadIdx.x >> 5;
  #pragma unroll
  for (int i = 0; i < 32; i += 8)
    tile[ty+i][tx] = A[(size_t)(r0+ty+i)*C + c0+tx];
  __syncthreads();
  #pragma unroll
  for (int i = 0; i < 32; i += 8)
    o[(size_t)(c0+ty+i)*R + (r0+tx)] = bf16r(tile[tx][ty+i] * scale);
}

__global__ __launch_bounds__(256) void prep_kernel(
    const float* __restrict__ x, unsigned short* __restrict__ xh,
    const float* __restrict__ Wq, const float* __restrict__ Wk, const float* __restrict__ Wv,
    unsigned short* __restrict__ WT,
    const float* __restrict__ Wu, unsigned short* __restrict__ WuT,
    const float* __restrict__ sp, const float* __restrict__ mvals,
    int* __restrict__ idx_out, float* __restrict__ w_out){
  __shared__ float tile[32][33];
  __shared__ int   s_idx[P_];
  __shared__ float s_dens[P_][M_];
  __shared__ float s_col[M_];
  const int bid = blockIdx.x;
  const float sc = 0.29730177875068026f; // 128^-0.25

  if (bid < 512){
    const int i = (bid*256 + threadIdx.x)*4;
    float4 v = *(const float4*)(x + i);
    uint2 pck = { pack_bf16x2(v.x, v.y), pack_bf16x2(v.z, v.w) };
    *(uint2*)(xh + i) = pck;
    return;
  }
  if (bid < 896){
    const int zz = bid - 512;
    const int z = zz >> 7, rem = zz & 127;
    const int by = rem >> 5, bx = rem & 31;       // R=128: 4 rows of 32; C=1024: 32 cols
    const float* A = (z==0) ? Wq : (z==1) ? Wk : Wv;
    tconv_body(A, WT + (size_t)z*1024*128, 128, 1024, by*32, bx*32, (z<2)?sc:1.0f, tile);
    return;
  }
  if (bid < 1024){
    const int idx2 = bid - 896;
    const int by = idx2 >> 2, bx = idx2 & 3;      // R=1024: 32, C=128: 4
    tconv_body(Wu, WuT, 1024, 128, by*32, bx*32, 1.0f, tile);
    return;
  }

  // ---- idx + weights: bt = bid - 1024 ----
  const int bt = bid - 1024;
  const int t  = bt & (T_-1);
  const int p  = threadIdx.x;

  const float dil  = sp[0];
  const float xs   = sp[1] + 2.0f;
  const float sigma = xs + log1pf(expf(-xs)) + 1e-7f;

  if (p < P_){
    const int m = p >> 2, j = p & 3;
    const float mean = fminf(fmaxf((float)t + (float)(m-4)*dil, 0.f), (float)(T_-1));
    int id;
    if      (j == 0) id = (int)floorf(mean);
    else if (j == 1) id = min((int)floorf(mean) + 1, T_-1);
    else {
      const unsigned f = ((unsigned)bt * M_ + (unsigned)m) * GADD_ + (unsigned)(j-2);
      id = (int)glob_rand(f);
    }
    s_idx[p] = id;
  }
  __syncthreads();
  if (p < P_){
    const int myid = s_idx[p];
    bool dup = false;
    for (int q = 0; q < p; ++q) dup |= (s_idx[q] == myid);
    const float pf = (float)myid;
    #pragma unroll
    for (int m = 0; m < M_; ++m){
      const float mean = fminf(fmaxf((float)t + (float)(m-4)*dil, 0.f), (float)(T_-1));
      const float d = (pf - mean) / sigma;
      s_dens[p][m] = dup ? 0.f : expf(-0.5f * d * d);
    }
  }
  __syncthreads();
  if (p < M_){
    float s = 0.f;
    for (int q = 0; q < P_; ++q) s += s_dens[q][p];
    s_col[p] = s;
  }
  __syncthreads();
  if (p < P_){
    float w = 0.f;
    #pragma unroll
    for (int m = 0; m < M_; ++m) w += s_dens[p][m] / s_col[m] * mvals[m];
    idx_out[bt*P_ + p] = s_idx[p];
    w_out[bt*P_ + p]   = w;
  }
}

// ---------------- kernel 2: QKV via MFMA, all outputs bf16 ----------------
// grid (16, 64, 3), 256 thr = 4 waves; wave: 16M x 64N, K=128.
__global__ __launch_bounds__(256) void qkv_mfma_kernel(const unsigned short* __restrict__ xh,
    const unsigned short* __restrict__ WT,
    unsigned short* __restrict__ Qh, unsigned short* __restrict__ Kh,
    unsigned short* __restrict__ Vh){
  const int z  = blockIdx.z;
  const int w  = threadIdx.x >> 6, l = threadIdx.x & 63;
  const int m0 = blockIdx.y*64 + w*16;
  const int n0 = blockIdx.x*64;
  const int lr = l & 15, lk = l >> 4;

  const unsigned short* __restrict__ WTz = WT + (size_t)z * 1024 * 128;
  unsigned short* __restrict__ Outh = (z==0) ? Qh : (z==1) ? Kh : Vh;

  bf16x8 a[4];
  #pragma unroll
  for (int kc = 0; kc < 4; ++kc)
    a[kc] = *(const bf16x8*)(xh + (size_t)(m0+lr)*128 + kc*32 + lk*8);

  f32x4 acc[4] = {};
  #pragma unroll
  for (int nf = 0; nf < 4; ++nf){
    #pragma unroll
    for (int kc = 0; kc < 4; ++kc){
      bf16x8 b = *(const bf16x8*)(WTz + (size_t)(n0+nf*16+lr)*128 + kc*32 + lk*8);
      acc[nf] = __builtin_amdgcn_mfma_f32_16x16x32_bf16(a[kc], b, acc[nf], 0, 0, 0);
    }
  }
  #pragma unroll
  for (int nf = 0; nf < 4; ++nf){
    const int col = n0 + nf*16 + lr;
    #pragma unroll
    for (int r = 0; r < 4; ++r)
      Outh[(size_t)(m0 + lk*4 + r)*1024 + col] = bf16r(acc[nf][r]);
  }
}

// ---------------- kernel 3: gather-attention (pair-loads, LDS transpose-reduce) ----------------
// One block per (b,t); 8 waves = 8 heads. Lane: half=lane>>5 owns point 2c+half,
// li=lane&31 owns dims li*4..li*4+3 (uint2 = 4 bf16 per load).
#define RSTR 37
__global__ __launch_bounds__(512) void attn_kernel(const unsigned short* __restrict__ Qh,
    const unsigned short* __restrict__ K, const unsigned short* __restrict__ V,
    const int* __restrict__ idx, const float* __restrict__ wts,
    unsigned short* __restrict__ outh){
  const int bid = blockIdx.x;
  const int bt  = ((bid & 7) << 9) | (bid >> 3);   // XCD swizzle, bijective
  const int b   = bt >> 11;
  const int h    = threadIdx.x >> 6, lane = threadIdx.x & 63;
  const int half = lane >> 5, li = lane & 31;

  __shared__ int   s_koff[P_];
  __shared__ float s_w[P_];
  __shared__ float s_red[NH_][32*RSTR];   // 37888 B
  __shared__ float s_a[NH_][36];

  if (threadIdx.x < P_){
    s_koff[threadIdx.x] = idx[bt*P_ + threadIdx.x] << 10;   // ip*1024 elements
    s_w[threadIdx.x]    = wts[bt*P_ + threadIdx.x];
  }
  __syncthreads();

  const size_t rowBase = (size_t)bt*1024 + h*EMB_;
  const uint2 qu = *(const uint2*)(Qh + rowBase + li*4);
  const float q0 = bflo(qu.x), q1 = bfhi(qu.x), q2 = bflo(qu.y), q3 = bfhi(qu.y);
  const unsigned short* __restrict__ Kb = K + (size_t)b*T_*1024 + h*EMB_ + li*4;
  const unsigned short* __restrict__ Vb = V + (size_t)b*T_*1024 + h*EMB_ + li*4;

  int ko[18];
  #pragma unroll
  for (int c = 0; c < 18; ++c) ko[c] = s_koff[2*c + half];

  // ---- Phase A: 18 uint2 loads, 4-dim partial dots ----
  float pr[18];
  #pragma unroll
  for (int c = 0; c < 18; ++c){
    const uint2 u = *(const uint2*)(Kb + ko[c]);
    pr[c] = q0*bflo(u.x) + q1*bfhi(u.x) + q2*bflo(u.y) + q3*bfhi(u.y);
  }

  // ---- Phase B: LDS transpose (no shuffles), column sum over 32 li-rows ----
  float* __restrict__ red = s_red[h];
  {
    float* __restrict__ dst = red + li*RSTR + half;
    #pragma unroll
    for (int c = 0; c < 18; ++c) dst[2*c] = pr[c];
  }
  const int pcol = (lane < P_) ? lane : 0;
  float s0=0.f, s1=0.f, s2=0.f, s3=0.f;
  #pragma unroll
  for (int r = 0; r < 32; r += 4){
    s0 += red[(r+0)*RSTR + pcol];
    s1 += red[(r+1)*RSTR + pcol];
    s2 += red[(r+2)*RSTR + pcol];
    s3 += red[(r+3)*RSTR + pcol];
  }
  const float logit = (s0+s1)+(s2+s3);

  // ---- softmax (lane-per-point) ----
  float val = (lane < P_) ? logit * s_w[pcol] : -INFINITY;
  float mx = val;
  #pragma unroll
  for (int off = 32; off; off >>= 1) mx = fmaxf(mx, __shfl_xor(mx, off));
  float e = (lane < P_) ? expf(val - mx) : 0.f;
  float s = e;
  #pragma unroll
  for (int off = 32; off; off >>= 1) s += __shfl_xor(s, off);
  if (lane < P_) s_a[h][lane] = e / s;

  // ---- Phase C: 18 uint2 V loads, weighted accumulate over own half's points ----
  float a0=0.f, a1=0.f, a2=0.f, a3=0.f;
  #pragma unroll
  for (int c = 0; c < 18; ++c){
    const float aw = s_a[h][2*c + half];
    const uint2 u = *(const uint2*)(Vb + ko[c]);
    a0 += aw*bflo(u.x); a1 += aw*bfhi(u.x);
    a2 += aw*bflo(u.y); a3 += aw*bfhi(u.y);
  }
  a0 += __shfl_xor(a0, 32); a1 += __shfl_xor(a1, 32);
  a2 += __shfl_xor(a2, 32); a3 += __shfl_xor(a3, 32);
  if (half == 0){
    uint2 pck = { pack_bf16x2(a0, a1), pack_bf16x2(a2, a3) };
    *(uint2*)(outh + rowBase + li*4) = pck;
  }
}

// ---------------- kernel 4: output GEMM via MFMA + bias ----------------
// out(4096x128) = attnh(4096x1024) @ Wu + bu; WuT[128][1024] bf16.
// grid (8, 64), 256 thr = 4 waves; wave: one 16x16 tile, K=1024, 2 acc chains.
__global__ __launch_bounds__(256) void out_mfma_kernel(const unsigned short* __restrict__ Ah,
    const unsigned short* __restrict__ WuT, const float* __restrict__ bu,
    float* __restrict__ out){
  const int w  = threadIdx.x >> 6, l = threadIdx.x & 63;
  const int m0 = blockIdx.y*64 + w*16;
  const int n0 = blockIdx.x*16;
  const int lr = l & 15, lk = l >> 4;

  const unsigned short* __restrict__ arow = Ah  + (size_t)(m0+lr)*1024 + lk*8;
  const unsigned short* __restrict__ brow = WuT + (size_t)(n0+lr)*1024 + lk*8;

  f32x4 accA = {}, accB = {};
  #pragma unroll 8
  for (int kc = 0; kc < 32; kc += 2){
    bf16x8 a0 = *(const bf16x8*)(arow + kc*32);
    bf16x8 b0 = *(const bf16x8*)(brow + kc*32);
    accA = __builtin_amdgcn_mfma_f32_16x16x32_bf16(a0, b0, accA, 0, 0, 0);
    bf16x8 a1 = *(const bf16x8*)(arow + (kc+1)*32);
    bf16x8 b1 = *(const bf16x8*)(brow + (kc+1)*32);
    accB = __builtin_amdgcn_mfma_f32_16x16x32_bf16(a1, b1, accB, 0, 0, 0);
  }
  const int c0 = n0 + lr;
  const float bias = bu[c0];
  #pragma unroll
  for (int r = 0; r < 4; ++r){
    const size_t row = (size_t)(m0 + lk*4 + r);
    out[row*128 + c0] = (accA[r] + accB[r]) + bias;
  }
}

// ---------------- launch ----------------
extern "C" void kernel_launch(void* const* d_in, const int* in_sizes, int n_in,
                              void* d_out, int out_size, void* d_ws, size_t ws_size,
                              hipStream_t stream){
  (void)in_sizes; (void)n_in; (void)out_size; (void)ws_size;
  const float* x    = (const float*)d_in[0];
  const float* sp   = (const float*)d_in[1];
  const float* mvl  = (const float*)d_in[2];
  const float* Wq   = (const float*)d_in[3];
  const float* Wk   = (const float*)d_in[4];
  const float* Wv   = (const float*)d_in[5];
  const float* Wu   = (const float*)d_in[6];
  const float* bu   = (const float*)d_in[7];
  float* out = (float*)d_out;

  const size_t n = (size_t)B_*NH_*T_*EMB_;               // 4,194,304
  unsigned short* Qh    = (unsigned short*)d_ws;         // n bf16
  unsigned short* Kh    = Qh + n;                        // n bf16
  unsigned short* Vh    = Kh + n;                        // n bf16
  unsigned short* attnh = Vh + n;                        // n bf16
  unsigned short* xh    = attnh + n;                     // 524288 bf16
  unsigned short* WT    = xh + (size_t)B_*T_*EMB_;       // 3*131072 bf16
  unsigned short* WuT   = WT + 3*131072;                 // 131072 bf16
  int*            idxb  = (int*)(WuT + 131072);
  float*          wb    = (float*)(idxb + (size_t)B_*T_*P_);

  prep_kernel<<<5120, 256, 0, stream>>>(x, xh, Wq, Wk, Wv, WT, Wu, WuT, sp, mvl, idxb, wb);
  qkv_mfma_kernel<<<dim3(16, 64, 3), 256, 0, stream>>>(xh, WT, Qh, Kh, Vh);
  attn_kernel<<<B_*T_, 512, 0, stream>>>(Qh, Kh, Vh, idxb, wb, attnh);
  out_mfma_kernel<<<dim3(8, 64), 256, 0, stream>>>(attnh, WuT, bu, out);
}

// Round 11
// 103.664 us; speedup vs baseline: 1.2113x; 1.0286x over previous
//
#include <hip/hip_runtime.h>
#include <math.h>

#define B_    2
#define T_    2048
#define EMB_  128
#define NH_   8
#define M_    9
#define P_    36
#define GADD_ 2

typedef _Float16 f16;
typedef __attribute__((ext_vector_type(2))) _Float16 f16x2;
typedef __attribute__((ext_vector_type(4))) _Float16 f16x4;
typedef __attribute__((ext_vector_type(8))) _Float16 f16x8;
typedef __attribute__((ext_vector_type(4))) float f32x4;

// ---------------- Threefry-2x32 (jax PRNG) ----------------
__device__ __forceinline__ unsigned rotl32(unsigned x, int r){ return (x<<r)|(x>>(32-r)); }

struct U2 { unsigned x, y; };

__device__ __forceinline__ U2 tf2x32(U2 key, U2 ctr){
  unsigned ks[3] = { key.x, key.y, key.x ^ key.y ^ 0x1BD11BDAu };
  unsigned x0 = ctr.x + ks[0], x1 = ctr.y + ks[1];
  const int rotA[4] = {13,15,26,6}, rotB[4] = {17,29,16,24};
  #pragma unroll
  for (int r = 0; r < 5; ++r){
    const int* rr = (r & 1) ? rotB : rotA;
    #pragma unroll
    for (int i = 0; i < 4; ++i){ x0 += x1; x1 = rotl32(x1, rr[i]); x1 ^= x0; }
    x0 += ks[(r+1)%3];
    x1 += ks[(r+2)%3] + (unsigned)(r+1);
  }
  return { x0, x1 };
}

// randint(key(42),(B,T,M,GADD),0,T), partitionable threefry path.
__device__ unsigned glob_rand(unsigned f){
  U2 k2 = tf2x32({0u, 42u}, {0u, 1u});
  U2 o  = tf2x32(k2, {0u, f});
  return (o.x ^ o.y) & (unsigned)(T_-1);
}

__device__ __forceinline__ f16x2 as_f16x2(unsigned u){ return __builtin_bit_cast(f16x2, u); }
__device__ __forceinline__ unsigned as_u32(f16x2 v){ return __builtin_bit_cast(unsigned, v); }

// ---------------- kernel 0: fused prep ----------------
__device__ __forceinline__ void tconv_body(const float* __restrict__ A,
    f16* __restrict__ o, int R, int C, int r0, int c0, float scale,
    float (*tile)[33]){
  const int tx = threadIdx.x & 31, ty = threadIdx.x >> 5;
  #pragma unroll
  for (int i = 0; i < 32; i += 8)
    tile[ty+i][tx] = A[(size_t)(r0+ty+i)*C + c0+tx];
  __syncthreads();
  #pragma unroll
  for (int i = 0; i < 32; i += 8)
    o[(size_t)(c0+ty+i)*R + (r0+tx)] = (f16)(tile[tx][ty+i] * scale);
}

__global__ __launch_bounds__(256) void prep_kernel(
    const float* __restrict__ x, f16* __restrict__ xh,
    const float* __restrict__ Wq, const float* __restrict__ Wk, const float* __restrict__ Wv,
    f16* __restrict__ WT,
    const float* __restrict__ Wu, f16* __restrict__ WuT,
    const float* __restrict__ sp, const float* __restrict__ mvals,
    int* __restrict__ idx_out, float* __restrict__ w_out){
  __shared__ float tile[32][33];
  __shared__ int   s_idx[4][P_];
  __shared__ float s_dens[4][P_][M_];
  __shared__ float s_col[4][M_];
  const int bid = blockIdx.x;
  const float sc = 0.29730177875068026f; // 128^-0.25

  if (bid < 512){
    const int i = (bid*256 + threadIdx.x)*4;
    float4 v = *(const float4*)(x + i);
    f16x4 p = { (f16)v.x, (f16)v.y, (f16)v.z, (f16)v.w };
    *(f16x4*)(xh + i) = p;
    return;
  }
  if (bid < 896){
    const int zz = bid - 512;
    const int z = zz >> 7, rem = zz & 127;
    const int by = rem >> 5, bx = rem & 31;       // [128][1024]: 4 x 32 tiles
    const float* A = (z==0) ? Wq : (z==1) ? Wk : Wv;
    tconv_body(A, WT + (size_t)z*1024*128, 128, 1024, by*32, bx*32, (z<2)?sc:1.0f, tile);
    return;
  }
  if (bid < 1024){
    const int idx2 = bid - 896;
    const int by = idx2 >> 2, bx = idx2 & 3;      // [1024][128]: 32 x 4 tiles
    tconv_body(Wu, WuT, 1024, 128, by*32, bx*32, 1.0f, tile);
    return;
  }

  // ---- idx + weights: 4 bt per block (one per wave) ----
  const int g  = threadIdx.x >> 6;
  const int p  = threadIdx.x & 63;
  const int bt = (bid - 1024)*4 + g;
  const int t  = bt & (T_-1);

  const float dil  = sp[0];
  const float xs   = sp[1] + 2.0f;
  const float sigma = xs + log1pf(expf(-xs)) + 1e-7f;

  if (p < P_){
    const int m = p >> 2, j = p & 3;
    const float mean = fminf(fmaxf((float)t + (float)(m-4)*dil, 0.f), (float)(T_-1));
    int id;
    if      (j == 0) id = (int)floorf(mean);
    else if (j == 1) id = min((int)floorf(mean) + 1, T_-1);
    else {
      const unsigned f = ((unsigned)bt * M_ + (unsigned)m) * GADD_ + (unsigned)(j-2);
      id = (int)glob_rand(f);
    }
    s_idx[g][p] = id;
  }
  __syncthreads();
  if (p < P_){
    const int myid = s_idx[g][p];
    bool dup = false;
    for (int q = 0; q < p; ++q) dup |= (s_idx[g][q] == myid);
    const float pf = (float)myid;
    #pragma unroll
    for (int m = 0; m < M_; ++m){
      const float mean = fminf(fmaxf((float)t + (float)(m-4)*dil, 0.f), (float)(T_-1));
      const float d = (pf - mean) / sigma;
      s_dens[g][p][m] = dup ? 0.f : expf(-0.5f * d * d);
    }
  }
  __syncthreads();
  if (p < M_){
    float s = 0.f;
    for (int q = 0; q < P_; ++q) s += s_dens[g][q][p];
    s_col[g][p] = s;
  }
  __syncthreads();
  if (p < P_){
    float w = 0.f;
    #pragma unroll
    for (int m = 0; m < M_; ++m) w += s_dens[g][p][m] / s_col[g][m] * mvals[m];
    idx_out[bt*P_ + p] = s_idx[g][p];
    w_out[bt*P_ + p]   = w;
  }
}

// ---------------- kernel 2: QKV via f16 MFMA ----------------
// grid (16, 64, 3), 256 thr = 4 waves; wave: 16M x 64N, K=128.
__global__ __launch_bounds__(256) void qkv_mfma_kernel(const f16* __restrict__ xh,
    const f16* __restrict__ WT,
    f16* __restrict__ Qh, f16* __restrict__ Kh, f16* __restrict__ Vh){
  const int z  = blockIdx.z;
  const int w  = threadIdx.x >> 6, l = threadIdx.x & 63;
  const int m0 = blockIdx.y*64 + w*16;
  const int n0 = blockIdx.x*64;
  const int lr = l & 15, lk = l >> 4;

  const f16* __restrict__ WTz = WT + (size_t)z * 1024 * 128;
  f16* __restrict__ Outh = (z==0) ? Qh : (z==1) ? Kh : Vh;

  f16x8 a[4];
  #pragma unroll
  for (int kc = 0; kc < 4; ++kc)
    a[kc] = *(const f16x8*)(xh + (size_t)(m0+lr)*128 + kc*32 + lk*8);

  f32x4 acc[4] = {};
  #pragma unroll
  for (int nf = 0; nf < 4; ++nf){
    #pragma unroll
    for (int kc = 0; kc < 4; ++kc){
      f16x8 b = *(const f16x8*)(WTz + (size_t)(n0+nf*16+lr)*128 + kc*32 + lk*8);
      acc[nf] = __builtin_amdgcn_mfma_f32_16x16x32_f16(a[kc], b, acc[nf], 0, 0, 0);
    }
  }
  #pragma unroll
  for (int nf = 0; nf < 4; ++nf){
    const int col = n0 + nf*16 + lr;
    #pragma unroll
    for (int r = 0; r < 4; ++r)
      Outh[(size_t)(m0 + lk*4 + r)*1024 + col] = (f16)acc[nf][r];
  }
}

// ---------------- kernel 3: gather-attention (f16 dot2 / pk_fma) ----------------
// One block per (b,t); 8 waves = 8 heads. half=lane>>5 owns point 2c+half,
// li=lane&31 owns dims li*4..li*4+3 (uint2 = 4 f16 per load).
#define RSTR 37
__global__ __launch_bounds__(512) void attn_kernel(const f16* __restrict__ Qh,
    const f16* __restrict__ K, const f16* __restrict__ V,
    const int* __restrict__ idx, const float* __restrict__ wts,
    f16* __restrict__ outh){
  const int bid = blockIdx.x;
  const int bt  = ((bid & 7) << 9) | (bid >> 3);   // XCD swizzle, bijective
  const int b   = bt >> 11;
  const int h    = threadIdx.x >> 6, lane = threadIdx.x & 63;
  const int half = lane >> 5, li = lane & 31;

  __shared__ int   s_koff[P_];
  __shared__ float s_w[P_];
  __shared__ float s_red[NH_][32*RSTR];
  __shared__ float s_a[NH_][36];

  if (threadIdx.x < P_){
    s_koff[threadIdx.x] = idx[bt*P_ + threadIdx.x] << 10;   // element offset ip*1024
    s_w[threadIdx.x]    = wts[bt*P_ + threadIdx.x];
  }
  __syncthreads();

  const size_t rowBase = (size_t)bt*1024 + h*EMB_;
  const uint2 qu = *(const uint2*)(Qh + rowBase + li*4);
  const f16x2 q01 = as_f16x2(qu.x), q23 = as_f16x2(qu.y);
  const f16* __restrict__ Kb = K + (size_t)b*T_*1024 + h*EMB_ + li*4;
  const f16* __restrict__ Vb = V + (size_t)b*T_*1024 + h*EMB_ + li*4;

  int ko[18];
  #pragma unroll
  for (int c = 0; c < 18; ++c) ko[c] = s_koff[2*c + half];

  // ---- Phase A: 18 uint2 loads, v_dot2_f32_f16 partial dots ----
  float pr[18];
  #pragma unroll
  for (int c = 0; c < 18; ++c){
    const uint2 u = *(const uint2*)(Kb + ko[c]);
    pr[c] = __builtin_amdgcn_fdot2(as_f16x2(u.x), q01,
            __builtin_amdgcn_fdot2(as_f16x2(u.y), q23, 0.f, false), false);
  }

  // ---- Phase B: LDS transpose (no shuffles), column sum over 32 li-rows ----
  float* __restrict__ red = s_red[h];
  {
    float* __restrict__ dst = red + li*RSTR + half;
    #pragma unroll
    for (int c = 0; c < 18; ++c) dst[2*c] = pr[c];
  }
  const int pcol = (lane < P_) ? lane : 0;
  float s0=0.f, s1=0.f, s2=0.f, s3=0.f;
  #pragma unroll
  for (int r = 0; r < 32; r += 4){
    s0 += red[(r+0)*RSTR + pcol];
    s1 += red[(r+1)*RSTR + pcol];
    s2 += red[(r+2)*RSTR + pcol];
    s3 += red[(r+3)*RSTR + pcol];
  }
  const float logit = (s0+s1)+(s2+s3);

  // ---- softmax (lane-per-point) ----
  float val = (lane < P_) ? logit * s_w[pcol] : -INFINITY;
  float mx = val;
  #pragma unroll
  for (int off = 32; off; off >>= 1) mx = fmaxf(mx, __shfl_xor(mx, off));
  float e = (lane < P_) ? expf(val - mx) : 0.f;
  float s = e;
  #pragma unroll
  for (int off = 32; off; off >>= 1) s += __shfl_xor(s, off);
  if (lane < P_) s_a[h][lane] = e / s;

  // ---- Phase C: 18 uint2 V loads, packed f16 fma accumulate ----
  f16x2 acc01 = {(f16)0.f, (f16)0.f}, acc23 = {(f16)0.f, (f16)0.f};
  #pragma unroll
  for (int c = 0; c < 18; ++c){
    const f16 awh = (f16)s_a[h][2*c + half];
    const f16x2 vw = { awh, awh };
    const uint2 u = *(const uint2*)(Vb + ko[c]);
    acc01 = vw * as_f16x2(u.x) + acc01;
    acc23 = vw * as_f16x2(u.y) + acc23;
  }
  acc01 = acc01 + as_f16x2(__shfl_xor((int)as_u32(acc01), 32));
  acc23 = acc23 + as_f16x2(__shfl_xor((int)as_u32(acc23), 32));
  if (half == 0){
    uint2 pck = { as_u32(acc01), as_u32(acc23) };
    *(uint2*)(outh + rowBase + li*4) = pck;
  }
}

// ---------------- kernel 4a: output GEMM, split-K f16 MFMA partials ----------------
// grid (4 kc, 64 m); block 4 waves; wave: 16M x 128N (8 frags), K-chunk 256.
__global__ __launch_bounds__(256) void out_partial_mfma(const f16* __restrict__ Ah,
    const f16* __restrict__ WuT, float* __restrict__ part){
  const int w  = threadIdx.x >> 6, l = threadIdx.x & 63;
  const int m0 = blockIdx.y*64 + w*16;
  const int k0 = blockIdx.x*256;
  const int lr = l & 15, lk = l >> 4;

  const f16* __restrict__ arow = Ah + (size_t)(m0+lr)*1024 + k0 + lk*8;
  f32x4 acc[8] = {};
  #pragma unroll
  for (int kc = 0; kc < 8; ++kc){
    f16x8 a = *(const f16x8*)(arow + kc*32);
    #pragma unroll
    for (int nf = 0; nf < 8; ++nf){
      f16x8 b = *(const f16x8*)(WuT + (size_t)(nf*16+lr)*1024 + k0 + kc*32 + lk*8);
      acc[nf] = __builtin_amdgcn_mfma_f32_16x16x32_f16(a, b, acc[nf], 0, 0, 0);
    }
  }
  float* __restrict__ dst = part + (size_t)blockIdx.x * (4096*128);
  #pragma unroll
  for (int nf = 0; nf < 8; ++nf){
    const int col = nf*16 + lr;
    #pragma unroll
    for (int r = 0; r < 4; ++r)
      dst[(size_t)(m0 + lk*4 + r)*128 + col] = acc[nf][r];
  }
}

// ---------------- kernel 4b: reduce partials + bias ----------------
__global__ __launch_bounds__(256) void out_reduce_kernel(const float* __restrict__ part,
    const float* __restrict__ bu, float* __restrict__ out){
  const int i = blockIdx.x * 256 + threadIdx.x;          // float4 index
  const int c0 = (i & 31) * 4;
  float4 acc = *(const float4*)(bu + c0);
  #pragma unroll
  for (int kc = 0; kc < 4; ++kc){
    float4 v = *(const float4*)(part + (size_t)kc*(4096*128) + (size_t)i*4);
    acc.x += v.x; acc.y += v.y; acc.z += v.z; acc.w += v.w;
  }
  *(float4*)(out + (size_t)i*4) = acc;
}

// ---------------- launch ----------------
extern "C" void kernel_launch(void* const* d_in, const int* in_sizes, int n_in,
                              void* d_out, int out_size, void* d_ws, size_t ws_size,
                              hipStream_t stream){
  (void)in_sizes; (void)n_in; (void)out_size; (void)ws_size;
  const float* x    = (const float*)d_in[0];
  const float* sp   = (const float*)d_in[1];
  const float* mvl  = (const float*)d_in[2];
  const float* Wq   = (const float*)d_in[3];
  const float* Wk   = (const float*)d_in[4];
  const float* Wv   = (const float*)d_in[5];
  const float* Wu   = (const float*)d_in[6];
  const float* bu   = (const float*)d_in[7];
  float* out = (float*)d_out;

  const size_t n = (size_t)B_*NH_*T_*EMB_;       // 4,194,304
  f16*   Qh    = (f16*)d_ws;                     // n
  f16*   Kh    = Qh + n;                         // n
  f16*   Vh    = Kh + n;                         // n
  f16*   attnh = Vh + n;                         // n
  f16*   xh    = attnh + n;                      // 524288
  f16*   WT    = xh + (size_t)B_*T_*EMB_;        // 3*131072
  f16*   WuT   = WT + 3*131072;                  // 131072
  int*   idxb  = (int*)(WuT + 131072);           // 147456
  float* wb    = (float*)(idxb + (size_t)B_*T_*P_); // 147456
  float* part  = wb + (size_t)B_*T_*P_;          // 4 * 524288 f32

  prep_kernel<<<2048, 256, 0, stream>>>(x, xh, Wq, Wk, Wv, WT, Wu, WuT, sp, mvl, idxb, wb);
  qkv_mfma_kernel<<<dim3(16, 64, 3), 256, 0, stream>>>(xh, WT, Qh, Kh, Vh);
  attn_kernel<<<B_*T_, 512, 0, stream>>>(Qh, Kh, Vh, idxb, wb, attnh);
  out_partial_mfma<<<dim3(4, 64), 256, 0, stream>>>(attnh, WuT, part);
  out_reduce_kernel<<<512, 256, 0, stream>>>(part, bu, out);
}

// Round 12
// 102.940 us; speedup vs baseline: 1.2198x; 1.0070x over previous
//
#include <hip/hip_runtime.h>
#include <math.h>

#define B_    2
#define T_    2048
#define EMB_  128
#define NH_   8
#define M_    9
#define P_    36
#define GADD_ 2

typedef _Float16 f16;
typedef __attribute__((ext_vector_type(2))) _Float16 f16x2;
typedef __attribute__((ext_vector_type(4))) _Float16 f16x4;
typedef __attribute__((ext_vector_type(8))) _Float16 f16x8;
typedef __attribute__((ext_vector_type(4))) float f32x4;

// ---------------- Threefry-2x32 (jax PRNG) ----------------
__device__ __forceinline__ unsigned rotl32(unsigned x, int r){ return (x<<r)|(x>>(32-r)); }

struct U2 { unsigned x, y; };

__device__ __forceinline__ U2 tf2x32(U2 key, U2 ctr){
  unsigned ks[3] = { key.x, key.y, key.x ^ key.y ^ 0x1BD11BDAu };
  unsigned x0 = ctr.x + ks[0], x1 = ctr.y + ks[1];
  const int rotA[4] = {13,15,26,6}, rotB[4] = {17,29,16,24};
  #pragma unroll
  for (int r = 0; r < 5; ++r){
    const int* rr = (r & 1) ? rotB : rotA;
    #pragma unroll
    for (int i = 0; i < 4; ++i){ x0 += x1; x1 = rotl32(x1, rr[i]); x1 ^= x0; }
    x0 += ks[(r+1)%3];
    x1 += ks[(r+2)%3] + (unsigned)(r+1);
  }
  return { x0, x1 };
}

// randint(key(42),(B,T,M,GADD),0,T), partitionable threefry path.
__device__ unsigned glob_rand(unsigned f){
  U2 k2 = tf2x32({0u, 42u}, {0u, 1u});
  U2 o  = tf2x32(k2, {0u, f});
  return (o.x ^ o.y) & (unsigned)(T_-1);
}

__device__ __forceinline__ f16x2 as_f16x2(unsigned u){ return __builtin_bit_cast(f16x2, u); }
__device__ __forceinline__ unsigned as_u32(f16x2 v){ return __builtin_bit_cast(unsigned, v); }

// ---------------- kernel 0: fused prep ----------------
__device__ __forceinline__ void tconv_body(const float* __restrict__ A,
    f16* __restrict__ o, int R, int C, int r0, int c0, float scale,
    float (*tile)[33]){
  const int tx = threadIdx.x & 31, ty = threadIdx.x >> 5;
  #pragma unroll
  for (int i = 0; i < 32; i += 8)
    tile[ty+i][tx] = A[(size_t)(r0+ty+i)*C + c0+tx];
  __syncthreads();
  #pragma unroll
  for (int i = 0; i < 32; i += 8)
    o[(size_t)(c0+ty+i)*R + (r0+tx)] = (f16)(tile[tx][ty+i] * scale);
}

__global__ __launch_bounds__(256) void prep_kernel(
    const float* __restrict__ x, f16* __restrict__ xh,
    const float* __restrict__ Wq, const float* __restrict__ Wk, const float* __restrict__ Wv,
    f16* __restrict__ WT,
    const float* __restrict__ Wu, f16* __restrict__ WuT,
    const float* __restrict__ sp, const float* __restrict__ mvals,
    int* __restrict__ idx_out, float* __restrict__ w_out){
  __shared__ float tile[32][33];
  __shared__ int   s_idx[4][P_];
  __shared__ float s_dens[4][P_][M_];
  __shared__ float s_col[4][M_];
  const int bid = blockIdx.x;
  const float sc = 0.29730177875068026f; // 128^-0.25

  if (bid < 512){
    const int i = (bid*256 + threadIdx.x)*4;
    float4 v = *(const float4*)(x + i);
    f16x4 p = { (f16)v.x, (f16)v.y, (f16)v.z, (f16)v.w };
    *(f16x4*)(xh + i) = p;
    return;
  }
  if (bid < 896){
    const int zz = bid - 512;
    const int z = zz >> 7, rem = zz & 127;
    const int by = rem >> 5, bx = rem & 31;       // [128][1024]: 4 x 32 tiles
    const float* A = (z==0) ? Wq : (z==1) ? Wk : Wv;
    tconv_body(A, WT + (size_t)z*1024*128, 128, 1024, by*32, bx*32, (z<2)?sc:1.0f, tile);
    return;
  }
  if (bid < 1024){
    const int idx2 = bid - 896;
    const int by = idx2 >> 2, bx = idx2 & 3;      // [1024][128]: 32 x 4 tiles
    tconv_body(Wu, WuT, 1024, 128, by*32, bx*32, 1.0f, tile);
    return;
  }

  // ---- idx + weights: 4 bt per block (one per wave) ----
  const int g  = threadIdx.x >> 6;
  const int p  = threadIdx.x & 63;
  const int bt = (bid - 1024)*4 + g;
  const int t  = bt & (T_-1);

  const float dil  = sp[0];
  const float xs   = sp[1] + 2.0f;
  const float sigma = xs + log1pf(expf(-xs)) + 1e-7f;

  if (p < P_){
    const int m = p >> 2, j = p & 3;
    const float mean = fminf(fmaxf((float)t + (float)(m-4)*dil, 0.f), (float)(T_-1));
    int id;
    if      (j == 0) id = (int)floorf(mean);
    else if (j == 1) id = min((int)floorf(mean) + 1, T_-1);
    else {
      const unsigned f = ((unsigned)bt * M_ + (unsigned)m) * GADD_ + (unsigned)(j-2);
      id = (int)glob_rand(f);
    }
    s_idx[g][p] = id;
  }
  __syncthreads();
  if (p < P_){
    const int myid = s_idx[g][p];
    bool dup = false;
    for (int q = 0; q < p; ++q) dup |= (s_idx[g][q] == myid);
    const float pf = (float)myid;
    #pragma unroll
    for (int m = 0; m < M_; ++m){
      const float mean = fminf(fmaxf((float)t + (float)(m-4)*dil, 0.f), (float)(T_-1));
      const float d = (pf - mean) / sigma;
      s_dens[g][p][m] = dup ? 0.f : expf(-0.5f * d * d);
    }
  }
  __syncthreads();
  if (p < M_){
    float s = 0.f;
    for (int q = 0; q < P_; ++q) s += s_dens[g][q][p];
    s_col[g][p] = s;
  }
  __syncthreads();
  if (p < P_){
    float w = 0.f;
    #pragma unroll
    for (int m = 0; m < M_; ++m) w += s_dens[g][p][m] / s_col[g][m] * mvals[m];
    idx_out[bt*P_ + p] = s_idx[g][p];
    w_out[bt*P_ + p]   = w;
  }
}

// ---------------- kernel 2: QKV via f16 MFMA ----------------
// grid (16, 64, 3), 256 thr = 4 waves; wave: 16M x 64N, K=128.
__global__ __launch_bounds__(256) void qkv_mfma_kernel(const f16* __restrict__ xh,
    const f16* __restrict__ WT,
    f16* __restrict__ Qh, f16* __restrict__ Kh, f16* __restrict__ Vh){
  const int z  = blockIdx.z;
  const int w  = threadIdx.x >> 6, l = threadIdx.x & 63;
  const int m0 = blockIdx.y*64 + w*16;
  const int n0 = blockIdx.x*64;
  const int lr = l & 15, lk = l >> 4;

  const f16* __restrict__ WTz = WT + (size_t)z * 1024 * 128;
  f16* __restrict__ Outh = (z==0) ? Qh : (z==1) ? Kh : Vh;

  f16x8 a[4];
  #pragma unroll
  for (int kc = 0; kc < 4; ++kc)
    a[kc] = *(const f16x8*)(xh + (size_t)(m0+lr)*128 + kc*32 + lk*8);

  f32x4 acc[4] = {};
  #pragma unroll
  for (int nf = 0; nf < 4; ++nf){
    #pragma unroll
    for (int kc = 0; kc < 4; ++kc){
      f16x8 b = *(const f16x8*)(WTz + (size_t)(n0+nf*16+lr)*128 + kc*32 + lk*8);
      acc[nf] = __builtin_amdgcn_mfma_f32_16x16x32_f16(a[kc], b, acc[nf], 0, 0, 0);
    }
  }
  #pragma unroll
  for (int nf = 0; nf < 4; ++nf){
    const int col = n0 + nf*16 + lr;
    #pragma unroll
    for (int r = 0; r < 4; ++r)
      Outh[(size_t)(m0 + lk*4 + r)*1024 + col] = (f16)acc[nf][r];
  }
}

// ---------------- kernel 3: gather-attention (V-loads hoisted ahead of softmax) ----------------
// One block per (b,t); 8 waves = 8 heads. half=lane>>5 owns point 2c+half,
// li=lane&31 owns dims li*4..li*4+3 (uint2 = 4 f16 per load).
#define RSTR 37
__global__ __launch_bounds__(512) void attn_kernel(const f16* __restrict__ Qh,
    const f16* __restrict__ K, const f16* __restrict__ V,
    const int* __restrict__ idx, const float* __restrict__ wts,
    f16* __restrict__ outh){
  const int bid = blockIdx.x;
  const int bt  = ((bid & 7) << 9) | (bid >> 3);   // XCD swizzle, bijective
  const int b   = bt >> 11;
  const int h    = threadIdx.x >> 6, lane = threadIdx.x & 63;
  const int half = lane >> 5, li = lane & 31;

  __shared__ int   s_koff[P_];
  __shared__ float s_w[P_];
  __shared__ float s_red[NH_][32*RSTR];
  __shared__ float s_a[NH_][36];

  if (threadIdx.x < P_){
    s_koff[threadIdx.x] = idx[bt*P_ + threadIdx.x] << 10;   // element offset ip*1024
    s_w[threadIdx.x]    = wts[bt*P_ + threadIdx.x];
  }
  __syncthreads();

  const size_t rowBase = (size_t)bt*1024 + h*EMB_;
  const uint2 qu = *(const uint2*)(Qh + rowBase + li*4);
  const f16x2 q01 = as_f16x2(qu.x), q23 = as_f16x2(qu.y);
  const f16* __restrict__ Kb = K + (size_t)b*T_*1024 + h*EMB_ + li*4;
  const f16* __restrict__ Vb = V + (size_t)b*T_*1024 + h*EMB_ + li*4;

  int ko[18];
  #pragma unroll
  for (int c = 0; c < 18; ++c) ko[c] = s_koff[2*c + half];

  // ---- Phase A: issue ALL gather loads (18 K + 18 V) before any reduction ----
  uint2 kU[18], vU[18];
  #pragma unroll
  for (int c = 0; c < 18; ++c) kU[c] = *(const uint2*)(Kb + ko[c]);
  #pragma unroll
  for (int c = 0; c < 18; ++c) vU[c] = *(const uint2*)(Vb + ko[c]);

  float pr[18];
  #pragma unroll
  for (int c = 0; c < 18; ++c){
    pr[c] = __builtin_amdgcn_fdot2(as_f16x2(kU[c].x), q01,
            __builtin_amdgcn_fdot2(as_f16x2(kU[c].y), q23, 0.f, false), false);
  }

  // ---- Phase B: LDS transpose (wave-local), column sum over 32 li-rows ----
  float* __restrict__ red = s_red[h];
  {
    float* __restrict__ dst = red + li*RSTR + half;
    #pragma unroll
    for (int c = 0; c < 18; ++c) dst[2*c] = pr[c];
  }
  const int pcol = (lane < P_) ? lane : 0;
  float s0=0.f, s1=0.f, s2=0.f, s3=0.f;
  #pragma unroll
  for (int r = 0; r < 32; r += 4){
    s0 += red[(r+0)*RSTR + pcol];
    s1 += red[(r+1)*RSTR + pcol];
    s2 += red[(r+2)*RSTR + pcol];
    s3 += red[(r+3)*RSTR + pcol];
  }
  const float logit = (s0+s1)+(s2+s3);

  // ---- softmax (lane-per-point) ----
  float val = (lane < P_) ? logit * s_w[pcol] : -INFINITY;
  float mx = val;
  #pragma unroll
  for (int off = 32; off; off >>= 1) mx = fmaxf(mx, __shfl_xor(mx, off));
  float e = (lane < P_) ? expf(val - mx) : 0.f;
  float s = e;
  #pragma unroll
  for (int off = 32; off; off >>= 1) s += __shfl_xor(s, off);
  if (lane < P_) s_a[h][lane] = e / s;

  // ---- Phase C: packed f16 fma accumulate from prefetched V registers ----
  f16x2 acc01 = {(f16)0.f, (f16)0.f}, acc23 = {(f16)0.f, (f16)0.f};
  #pragma unroll
  for (int c = 0; c < 18; ++c){
    const f16 awh = (f16)s_a[h][2*c + half];
    const f16x2 vw = { awh, awh };
    acc01 = vw * as_f16x2(vU[c].x) + acc01;
    acc23 = vw * as_f16x2(vU[c].y) + acc23;
  }
  acc01 = acc01 + as_f16x2(__shfl_xor((int)as_u32(acc01), 32));
  acc23 = acc23 + as_f16x2(__shfl_xor((int)as_u32(acc23), 32));
  if (half == 0){
    uint2 pck = { as_u32(acc01), as_u32(acc23) };
    *(uint2*)(outh + rowBase + li*4) = pck;
  }
}

// ---------------- kernel 4a: output GEMM, split-K f16 MFMA partials ----------------
// grid (4 kc, 64 m); block 4 waves; wave: 16M x 128N (8 frags), K-chunk 256.
__global__ __launch_bounds__(256) void out_partial_mfma(const f16* __restrict__ Ah,
    const f16* __restrict__ WuT, float* __restrict__ part){
  const int w  = threadIdx.x >> 6, l = threadIdx.x & 63;
  const int m0 = blockIdx.y*64 + w*16;
  const int k0 = blockIdx.x*256;
  const int lr = l & 15, lk = l >> 4;

  const f16* __restrict__ arow = Ah + (size_t)(m0+lr)*1024 + k0 + lk*8;
  f32x4 acc[8] = {};
  #pragma unroll
  for (int kc = 0; kc < 8; ++kc){
    f16x8 a = *(const f16x8*)(arow + kc*32);
    #pragma unroll
    for (int nf = 0; nf < 8; ++nf){
      f16x8 b = *(const f16x8*)(WuT + (size_t)(nf*16+lr)*1024 + k0 + kc*32 + lk*8);
      acc[nf] = __builtin_amdgcn_mfma_f32_16x16x32_f16(a, b, acc[nf], 0, 0, 0);
    }
  }
  float* __restrict__ dst = part + (size_t)blockIdx.x * (4096*128);
  #pragma unroll
  for (int nf = 0; nf < 8; ++nf){
    const int col = nf*16 + lr;
    #pragma unroll
    for (int r = 0; r < 4; ++r)
      dst[(size_t)(m0 + lk*4 + r)*128 + col] = acc[nf][r];
  }
}

// ---------------- kernel 4b: reduce partials + bias ----------------
__global__ __launch_bounds__(256) void out_reduce_kernel(const float* __restrict__ part,
    const float* __restrict__ bu, float* __restrict__ out){
  const int i = blockIdx.x * 256 + threadIdx.x;          // float4 index
  const int c0 = (i & 31) * 4;
  float4 acc = *(const float4*)(bu + c0);
  #pragma unroll
  for (int kc = 0; kc < 4; ++kc){
    float4 v = *(const float4*)(part + (size_t)kc*(4096*128) + (size_t)i*4);
    acc.x += v.x; acc.y += v.y; acc.z += v.z; acc.w += v.w;
  }
  *(float4*)(out + (size_t)i*4) = acc;
}

// ---------------- launch ----------------
extern "C" void kernel_launch(void* const* d_in, const int* in_sizes, int n_in,
                              void* d_out, int out_size, void* d_ws, size_t ws_size,
                              hipStream_t stream){
  (void)in_sizes; (void)n_in; (void)out_size; (void)ws_size;
  const float* x    = (const float*)d_in[0];
  const float* sp   = (const float*)d_in[1];
  const float* mvl  = (const float*)d_in[2];
  const float* Wq   = (const float*)d_in[3];
  const float* Wk   = (const float*)d_in[4];
  const float* Wv   = (const float*)d_in[5];
  const float* Wu   = (const float*)d_in[6];
  const float* bu   = (const float*)d_in[7];
  float* out = (float*)d_out;

  const size_t n = (size_t)B_*NH_*T_*EMB_;       // 4,194,304
  f16*   Qh    = (f16*)d_ws;                     // n
  f16*   Kh    = Qh + n;                         // n
  f16*   Vh    = Kh + n;                         // n
  f16*   attnh = Vh + n;                         // n
  f16*   xh    = attnh + n;                      // 524288
  f16*   WT    = xh + (size_t)B_*T_*EMB_;        // 3*131072
  f16*   WuT   = WT + 3*131072;                  // 131072
  int*   idxb  = (int*)(WuT + 131072);           // 147456
  float* wb    = (float*)(idxb + (size_t)B_*T_*P_); // 147456
  float* part  = wb + (size_t)B_*T_*P_;          // 4 * 524288 f32

  prep_kernel<<<2048, 256, 0, stream>>>(x, xh, Wq, Wk, Wv, WT, Wu, WuT, sp, mvl, idxb, wb);
  qkv_mfma_kernel<<<dim3(16, 64, 3), 256, 0, stream>>>(xh, WT, Qh, Kh, Vh);
  attn_kernel<<<B_*T_, 512, 0, stream>>>(Qh, Kh, Vh, idxb, wb, attnh);
  out_partial_mfma<<<dim3(4, 64), 256, 0, stream>>>(attnh, WuT, part);
  out_reduce_kernel<<<512, 256, 0, stream>>>(part, bu, out);
}

// Round 13
// 80.534 us; speedup vs baseline: 1.5591x; 1.2782x over previous
//
#include <hip/hip_runtime.h>
#include <math.h>

#define B_    2
#define T_    2048
#define EMB_  128
#define NH_   8
#define M_    9
#define P_    36
#define GADD_ 2

typedef _Float16 f16;
typedef __attribute__((ext_vector_type(2))) _Float16 f16x2;
typedef __attribute__((ext_vector_type(4))) _Float16 f16x4;
typedef __attribute__((ext_vector_type(8))) _Float16 f16x8;
typedef __attribute__((ext_vector_type(4))) float f32x4;

// ---------------- Threefry-2x32 (jax PRNG) ----------------
__device__ __forceinline__ unsigned rotl32(unsigned x, int r){ return (x<<r)|(x>>(32-r)); }

struct U2 { unsigned x, y; };

__device__ __forceinline__ U2 tf2x32(U2 key, U2 ctr){
  unsigned ks[3] = { key.x, key.y, key.x ^ key.y ^ 0x1BD11BDAu };
  unsigned x0 = ctr.x + ks[0], x1 = ctr.y + ks[1];
  const int rotA[4] = {13,15,26,6}, rotB[4] = {17,29,16,24};
  #pragma unroll
  for (int r = 0; r < 5; ++r){
    const int* rr = (r & 1) ? rotB : rotA;
    #pragma unroll
    for (int i = 0; i < 4; ++i){ x0 += x1; x1 = rotl32(x1, rr[i]); x1 ^= x0; }
    x0 += ks[(r+1)%3];
    x1 += ks[(r+2)%3] + (unsigned)(r+1);
  }
  return { x0, x1 };
}

// randint(key(42),(B,T,M,GADD),0,T), partitionable threefry path.
__device__ unsigned glob_rand(unsigned f){
  U2 k2 = tf2x32({0u, 42u}, {0u, 1u});
  U2 o  = tf2x32(k2, {0u, f});
  return (o.x ^ o.y) & (unsigned)(T_-1);
}

__device__ __forceinline__ f16x2 as_f16x2(unsigned u){ return __builtin_bit_cast(f16x2, u); }
__device__ __forceinline__ unsigned as_u32(f16x2 v){ return __builtin_bit_cast(unsigned, v); }

// ---------------- kernel 0: fused prep ----------------
__device__ __forceinline__ void tconv_body(const float* __restrict__ A,
    f16* __restrict__ o, int R, int C, int r0, int c0, float scale,
    float (*tile)[33]){
  const int tx = threadIdx.x & 31, ty = threadIdx.x >> 5;
  #pragma unroll
  for (int i = 0; i < 32; i += 8)
    tile[ty+i][tx] = A[(size_t)(r0+ty+i)*C + c0+tx];
  __syncthreads();
  #pragma unroll
  for (int i = 0; i < 32; i += 8)
    o[(size_t)(c0+ty+i)*R + (r0+tx)] = (f16)(tile[tx][ty+i] * scale);
}

__global__ __launch_bounds__(256) void prep_kernel(
    const float* __restrict__ x, f16* __restrict__ xh,
    const float* __restrict__ Wq, const float* __restrict__ Wk, const float* __restrict__ Wv,
    f16* __restrict__ WT,
    const float* __restrict__ Wu, f16* __restrict__ WuT,
    const float* __restrict__ sp, const float* __restrict__ mvals,
    int* __restrict__ idx_out, float* __restrict__ w_out){
  __shared__ float tile[32][33];
  __shared__ int   s_idx[4][P_];
  __shared__ float s_dens[4][P_][M_];
  __shared__ float s_col[4][M_];
  const int bid = blockIdx.x;
  const float sc = 0.29730177875068026f; // 128^-0.25

  if (bid < 512){
    const int i = (bid*256 + threadIdx.x)*4;
    float4 v = *(const float4*)(x + i);
    f16x4 p = { (f16)v.x, (f16)v.y, (f16)v.z, (f16)v.w };
    *(f16x4*)(xh + i) = p;
    return;
  }
  if (bid < 896){
    const int zz = bid - 512;
    const int z = zz >> 7, rem = zz & 127;
    const int by = rem >> 5, bx = rem & 31;       // [128][1024]: 4 x 32 tiles
    const float* A = (z==0) ? Wq : (z==1) ? Wk : Wv;
    tconv_body(A, WT + (size_t)z*1024*128, 128, 1024, by*32, bx*32, (z<2)?sc:1.0f, tile);
    return;
  }
  if (bid < 1024){
    const int idx2 = bid - 896;
    const int by = idx2 >> 2, bx = idx2 & 3;      // [1024][128]: 32 x 4 tiles
    tconv_body(Wu, WuT, 1024, 128, by*32, bx*32, 1.0f, tile);
    return;
  }

  // ---- idx + weights: 4 bt per block (one per wave) ----
  const int g  = threadIdx.x >> 6;
  const int p  = threadIdx.x & 63;
  const int bt = (bid - 1024)*4 + g;
  const int t  = bt & (T_-1);

  const float dil  = sp[0];
  const float xs   = sp[1] + 2.0f;
  const float sigma = xs + log1pf(expf(-xs)) + 1e-7f;

  if (p < P_){
    const int m = p >> 2, j = p & 3;
    const float mean = fminf(fmaxf((float)t + (float)(m-4)*dil, 0.f), (float)(T_-1));
    int id;
    if      (j == 0) id = (int)floorf(mean);
    else if (j == 1) id = min((int)floorf(mean) + 1, T_-1);
    else {
      const unsigned f = ((unsigned)bt * M_ + (unsigned)m) * GADD_ + (unsigned)(j-2);
      id = (int)glob_rand(f);
    }
    s_idx[g][p] = id;
  }
  __syncthreads();
  if (p < P_){
    const int myid = s_idx[g][p];
    bool dup = false;
    for (int q = 0; q < p; ++q) dup |= (s_idx[g][q] == myid);
    const float pf = (float)myid;
    #pragma unroll
    for (int m = 0; m < M_; ++m){
      const float mean = fminf(fmaxf((float)t + (float)(m-4)*dil, 0.f), (float)(T_-1));
      const float d = (pf - mean) / sigma;
      s_dens[g][p][m] = dup ? 0.f : expf(-0.5f * d * d);
    }
  }
  __syncthreads();
  if (p < M_){
    float s = 0.f;
    for (int q = 0; q < P_; ++q) s += s_dens[g][q][p];
    s_col[g][p] = s;
  }
  __syncthreads();
  if (p < P_){
    float w = 0.f;
    #pragma unroll
    for (int m = 0; m < M_; ++m) w += s_dens[g][p][m] / s_col[g][m] * mvals[m];
    idx_out[bt*P_ + p] = s_idx[g][p];
    w_out[bt*P_ + p]   = w;
  }
}

// ---------------- kernel 2: QKV via f16 MFMA, z-merged ----------------
// grid (16, 64), 256 thr = 4 waves; wave: 16M x 64N, K=128, 3 outputs.
__global__ __launch_bounds__(256) void qkv_mfma_kernel(const f16* __restrict__ xh,
    const f16* __restrict__ WT,
    f16* __restrict__ Qh, f16* __restrict__ Kh, f16* __restrict__ Vh){
  const int w  = threadIdx.x >> 6, l = threadIdx.x & 63;
  const int m0 = blockIdx.y*64 + w*16;
  const int n0 = blockIdx.x*64;
  const int lr = l & 15, lk = l >> 4;

  f16x8 a[4];
  #pragma unroll
  for (int kc = 0; kc < 4; ++kc)
    a[kc] = *(const f16x8*)(xh + (size_t)(m0+lr)*128 + kc*32 + lk*8);

  #pragma unroll
  for (int z = 0; z < 3; ++z){
    const f16* __restrict__ WTz = WT + (size_t)z * 1024 * 128;
    f16* __restrict__ Outh = (z==0) ? Qh : (z==1) ? Kh : Vh;
    f32x4 acc[4] = {};
    #pragma unroll
    for (int nf = 0; nf < 4; ++nf){
      #pragma unroll
      for (int kc = 0; kc < 4; ++kc){
        f16x8 b = *(const f16x8*)(WTz + (size_t)(n0+nf*16+lr)*128 + kc*32 + lk*8);
        acc[nf] = __builtin_amdgcn_mfma_f32_16x16x32_f16(a[kc], b, acc[nf], 0, 0, 0);
      }
    }
    #pragma unroll
    for (int nf = 0; nf < 4; ++nf){
      const int col = n0 + nf*16 + lr;
      #pragma unroll
      for (int r = 0; r < 4; ++r)
        Outh[(size_t)(m0 + lk*4 + r)*1024 + col] = (f16)acc[nf][r];
    }
  }
}

// ---------------- kernel 3: gather-attention (uint4 gathers, 4 pts/instr) ----------------
// grid (4096, 2), 256 thr = 4 waves = 4 heads (h = by*4 + w).
// Lane: pg=lane>>4 owns points 4c+pg (c=0..8); li=lane&15 owns dims li*8..+8.
#define RSTR 37
#define NHB  4
__global__ __launch_bounds__(256) void attn_kernel(const f16* __restrict__ Qh,
    const f16* __restrict__ K, const f16* __restrict__ V,
    const int* __restrict__ idx, const float* __restrict__ wts,
    f16* __restrict__ outh){
  const int bid = blockIdx.x;
  const int bt  = ((bid & 7) << 9) | (bid >> 3);   // XCD swizzle, bijective
  const int b   = bt >> 11;
  const int hw   = threadIdx.x >> 6, lane = threadIdx.x & 63;
  const int h    = blockIdx.y*NHB + hw;
  const int pg = lane >> 4, li = lane & 15;

  __shared__ int   s_koff[P_];
  __shared__ float s_w[P_];
  __shared__ float s_red[NHB][16*RSTR];
  __shared__ float s_a[NHB][36];

  if (threadIdx.x < P_){
    s_koff[threadIdx.x] = idx[bt*P_ + threadIdx.x] << 10;   // element offset ip*1024
    s_w[threadIdx.x]    = wts[bt*P_ + threadIdx.x];
  }
  __syncthreads();

  const size_t rowBase = (size_t)bt*1024 + h*EMB_;
  const uint4 qu = *(const uint4*)(Qh + rowBase + li*8);
  const f16x2 q01 = as_f16x2(qu.x), q23 = as_f16x2(qu.y);
  const f16x2 q45 = as_f16x2(qu.z), q67 = as_f16x2(qu.w);
  const f16* __restrict__ Kb = K + (size_t)b*T_*1024 + h*EMB_ + li*8;
  const f16* __restrict__ Vb = V + (size_t)b*T_*1024 + h*EMB_ + li*8;

  int ko[9];
  #pragma unroll
  for (int c = 0; c < 9; ++c) ko[c] = s_koff[4*c + pg];

  // ---- Phase A: 9 uint4 K loads; 8-dim partial dots ----
  uint4 kU[9];
  #pragma unroll
  for (int c = 0; c < 9; ++c) kU[c] = *(const uint4*)(Kb + ko[c]);

  float pr[9];
  #pragma unroll
  for (int c = 0; c < 9; ++c){
    pr[c] = __builtin_amdgcn_fdot2(as_f16x2(kU[c].x), q01,
            __builtin_amdgcn_fdot2(as_f16x2(kU[c].y), q23,
            __builtin_amdgcn_fdot2(as_f16x2(kU[c].z), q45,
            __builtin_amdgcn_fdot2(as_f16x2(kU[c].w), q67, 0.f, false),
            false), false), false);
  }

  // ---- Phase B: LDS transpose (wave-local), column sum over 16 li-rows ----
  float* __restrict__ red = s_red[hw];
  {
    float* __restrict__ dst = red + li*RSTR + pg;
    #pragma unroll
    for (int c = 0; c < 9; ++c) dst[4*c] = pr[c];
  }
  const int pcol = (lane < P_) ? lane : 0;
  float s0=0.f, s1=0.f, s2=0.f, s3=0.f;
  #pragma unroll
  for (int r = 0; r < 16; r += 4){
    s0 += red[(r+0)*RSTR + pcol];
    s1 += red[(r+1)*RSTR + pcol];
    s2 += red[(r+2)*RSTR + pcol];
    s3 += red[(r+3)*RSTR + pcol];
  }
  const float logit = (s0+s1)+(s2+s3);

  // ---- softmax (lane-per-point) ----
  float val = (lane < P_) ? logit * s_w[pcol] : -INFINITY;
  float mx = val;
  #pragma unroll
  for (int off = 32; off; off >>= 1) mx = fmaxf(mx, __shfl_xor(mx, off));
  float e = (lane < P_) ? expf(val - mx) : 0.f;
  float s = e;
  #pragma unroll
  for (int off = 32; off; off >>= 1) s += __shfl_xor(s, off);
  if (lane < P_) s_a[hw][lane] = e / s;

  // ---- Phase C: 9 uint4 V loads, packed f16 fma over own pg's points ----
  f16x2 a01 = {(f16)0.f,(f16)0.f}, a23 = a01, a45 = a01, a67 = a01;
  #pragma unroll
  for (int c = 0; c < 9; ++c){
    const f16 awh = (f16)s_a[hw][4*c + pg];
    const f16x2 vw = { awh, awh };
    const uint4 u = *(const uint4*)(Vb + ko[c]);
    a01 = vw * as_f16x2(u.x) + a01;
    a23 = vw * as_f16x2(u.y) + a23;
    a45 = vw * as_f16x2(u.z) + a45;
    a67 = vw * as_f16x2(u.w) + a67;
  }
  // fold over the 4 pg groups
  a01 = a01 + as_f16x2(__shfl_xor((int)as_u32(a01), 16));
  a23 = a23 + as_f16x2(__shfl_xor((int)as_u32(a23), 16));
  a45 = a45 + as_f16x2(__shfl_xor((int)as_u32(a45), 16));
  a67 = a67 + as_f16x2(__shfl_xor((int)as_u32(a67), 16));
  a01 = a01 + as_f16x2(__shfl_xor((int)as_u32(a01), 32));
  a23 = a23 + as_f16x2(__shfl_xor((int)as_u32(a23), 32));
  a45 = a45 + as_f16x2(__shfl_xor((int)as_u32(a45), 32));
  a67 = a67 + as_f16x2(__shfl_xor((int)as_u32(a67), 32));
  if (pg == 0){
    uint4 pck = { as_u32(a01), as_u32(a23), as_u32(a45), as_u32(a67) };
    *(uint4*)(outh + rowBase + li*8) = pck;
  }
}

// ---------------- kernel 4a: output GEMM, split-K f16 MFMA partials ----------------
// grid (4 kc, 64 m); block 4 waves; wave: 16M x 128N (8 frags), K-chunk 256.
__global__ __launch_bounds__(256) void out_partial_mfma(const f16* __restrict__ Ah,
    const f16* __restrict__ WuT, float* __restrict__ part){
  const int w  = threadIdx.x >> 6, l = threadIdx.x & 63;
  const int m0 = blockIdx.y*64 + w*16;
  const int k0 = blockIdx.x*256;
  const int lr = l & 15, lk = l >> 4;

  const f16* __restrict__ arow = Ah + (size_t)(m0+lr)*1024 + k0 + lk*8;
  f32x4 acc[8] = {};
  #pragma unroll
  for (int kc = 0; kc < 8; ++kc){
    f16x8 a = *(const f16x8*)(arow + kc*32);
    #pragma unroll
    for (int nf = 0; nf < 8; ++nf){
      f16x8 b = *(const f16x8*)(WuT + (size_t)(nf*16+lr)*1024 + k0 + kc*32 + lk*8);
      acc[nf] = __builtin_amdgcn_mfma_f32_16x16x32_f16(a, b, acc[nf], 0, 0, 0);
    }
  }
  float* __restrict__ dst = part + (size_t)blockIdx.x * (4096*128);
  #pragma unroll
  for (int nf = 0; nf < 8; ++nf){
    const int col = nf*16 + lr;
    #pragma unroll
    for (int r = 0; r < 4; ++r)
      dst[(size_t)(m0 + lk*4 + r)*128 + col] = acc[nf][r];
  }
}

// ---------------- kernel 4b: reduce partials + bias ----------------
__global__ __launch_bounds__(256) void out_reduce_kernel(const float* __restrict__ part,
    const float* __restrict__ bu, float* __restrict__ out){
  const int i = blockIdx.x * 256 + threadIdx.x;          // float4 index
  const int c0 = (i & 31) * 4;
  float4 acc = *(const float4*)(bu + c0);
  #pragma unroll
  for (int kc = 0; kc < 4; ++kc){
    float4 v = *(const float4*)(part + (size_t)kc*(4096*128) + (size_t)i*4);
    acc.x += v.x; acc.y += v.y; acc.z += v.z; acc.w += v.w;
  }
  *(float4*)(out + (size_t)i*4) = acc;
}

// ---------------- launch ----------------
extern "C" void kernel_launch(void* const* d_in, const int* in_sizes, int n_in,
                              void* d_out, int out_size, void* d_ws, size_t ws_size,
                              hipStream_t stream){
  (void)in_sizes; (void)n_in; (void)out_size; (void)ws_size;
  const float* x    = (const float*)d_in[0];
  const float* sp   = (const float*)d_in[1];
  const float* mvl  = (const float*)d_in[2];
  const float* Wq   = (const float*)d_in[3];
  const float* Wk   = (const float*)d_in[4];
  const float* Wv   = (const float*)d_in[5];
  const float* Wu   = (const float*)d_in[6];
  const float* bu   = (const float*)d_in[7];
  float* out = (float*)d_out;

  const size_t n = (size_t)B_*NH_*T_*EMB_;       // 4,194,304
  f16*   Qh    = (f16*)d_ws;                     // n
  f16*   Kh    = Qh + n;                         // n
  f16*   Vh    = Kh + n;                         // n
  f16*   attnh = Vh + n;                         // n
  f16*   xh    = attnh + n;                      // 524288
  f16*   WT    = xh + (size_t)B_*T_*EMB_;        // 3*131072
  f16*   WuT   = WT + 3*131072;                  // 131072
  int*   idxb  = (int*)(WuT + 131072);           // 147456
  float* wb    = (float*)(idxb + (size_t)B_*T_*P_); // 147456
  float* part  = wb + (size_t)B_*T_*P_;          // 4 * 524288 f32

  prep_kernel<<<2048, 256, 0, stream>>>(x, xh, Wq, Wk, Wv, WT, Wu, WuT, sp, mvl, idxb, wb);
  qkv_mfma_kernel<<<dim3(16, 64), 256, 0, stream>>>(xh, WT, Qh, Kh, Vh);
  attn_kernel<<<dim3(B_*T_, 2), 256, 0, stream>>>(Qh, Kh, Vh, idxb, wb, attnh);
  out_partial_mfma<<<dim3(4, 64), 256, 0, stream>>>(attnh, WuT, part);
  out_reduce_kernel<<<512, 256, 0, stream>>>(part, bu, out);
}